// Round 1
// baseline (1790.625 us; speedup 1.0000x reference)
//
#include <hip/hip_runtime.h>
#include <hip/hip_bf16.h>
#include <cstdint>
#include <cstddef>

namespace {

constexpr int Hh = 512;
constexpr int G3 = 1536;   // 3*H
constexpr int Bb = 32;
constexpr int Tt = 64;
constexpr int BT = 2048;   // B*T
constexpr int Vv = 32000;

typedef __attribute__((ext_vector_type(8))) short short8;
typedef __attribute__((ext_vector_type(4))) float f32x4;

// ---------------- f32 -> bf16 convert (vectorized) ----------------
__global__ void cvt_bf16_k(const float* __restrict__ src, __hip_bfloat16* __restrict__ dst, int n4) {
  int i = blockIdx.x * blockDim.x + threadIdx.x;
  if (i >= n4) return;
  float4 v = ((const float4*)src)[i];
  union { __hip_bfloat16 h[4]; uint2 u; } o;
  o.h[0] = __float2bfloat16(v.x);
  o.h[1] = __float2bfloat16(v.y);
  o.h[2] = __float2bfloat16(v.z);
  o.h[3] = __float2bfloat16(v.w);
  ((uint2*)dst)[i] = o.u;
}

// ---------------- transpose 1536x512 (from col0, ld) -> [512][1536] f32 ----------------
__global__ void transpose_k(const float* __restrict__ src, int ld, int col0, float* __restrict__ dst) {
  __shared__ float tile[32][33];
  int gx = blockIdx.x * 32;  // col in src (k), 0..511
  int gy = blockIdx.y * 32;  // row in src (gate-row), 0..1535
  int tx = threadIdx.x, ty = threadIdx.y;
  #pragma unroll
  for (int j = 0; j < 32; j += 8) {
    tile[ty + j][tx] = src[(size_t)(gy + ty + j) * ld + col0 + gx + tx];
  }
  __syncthreads();
  #pragma unroll
  for (int j = 0; j < 32; j += 8) {
    dst[(size_t)(gx + ty + j) * G3 + gy + tx] = tile[tx][ty + j];
  }
}

// ---------------- embedding gather (optionally relu) -> bf16 [2048][512] ----------------
__global__ void embed_k(const int* __restrict__ idx, const float* __restrict__ emb,
                        __hip_bfloat16* __restrict__ outp, int do_relu) {
  int row = blockIdx.x;            // 0..2047 (= b*64+t)
  int r = idx[row];
  float4 v = ((const float4*)(emb + (size_t)r * Hh))[threadIdx.x];  // 128 thr * 4
  if (do_relu) {
    v.x = fmaxf(v.x, 0.f); v.y = fmaxf(v.y, 0.f);
    v.z = fmaxf(v.z, 0.f); v.w = fmaxf(v.w, 0.f);
  }
  union { __hip_bfloat16 h[4]; uint2 u; } o;
  o.h[0] = __float2bfloat16(v.x);
  o.h[1] = __float2bfloat16(v.y);
  o.h[2] = __float2bfloat16(v.z);
  o.h[3] = __float2bfloat16(v.w);
  ((uint2*)(outp + (size_t)row * Hh))[threadIdx.x] = o.u;
}

// ---------------- zero f32 ----------------
__global__ void zero_k(float* __restrict__ p, int n) {
  int i = blockIdx.x * blockDim.x + threadIdx.x;
  if (i < n) p[i] = 0.f;
}

// ---------------- relu(thought)->bf16, padded to 128 rows ----------------
__global__ void thought_prep_k(const float* __restrict__ th, __hip_bfloat16* __restrict__ outp) {
  int row = blockIdx.x;  // 0..127
  float4 v = {0.f, 0.f, 0.f, 0.f};
  if (row < Bb) v = ((const float4*)(th + (size_t)row * Hh))[threadIdx.x];
  v.x = fmaxf(v.x, 0.f); v.y = fmaxf(v.y, 0.f);
  v.z = fmaxf(v.z, 0.f); v.w = fmaxf(v.w, 0.f);
  union { __hip_bfloat16 h[4]; uint2 u; } o;
  o.h[0] = __float2bfloat16(v.x);
  o.h[1] = __float2bfloat16(v.y);
  o.h[2] = __float2bfloat16(v.z);
  o.h[3] = __float2bfloat16(v.w);
  ((uint2*)(outp + (size_t)row * Hh))[threadIdx.x] = o.u;
}

// ---------------- bf16 MFMA GEMM: C[M,N](f32) = A[M,K] * B[N,K]^T (+bias1[n]) (+bias2[(m>>6)*1536+n]) ----------------
// tile 128x128, BK=64, 256 threads (4 waves, each 64x64), single-buffered LDS, reg-staged.
__global__ __launch_bounds__(256) void gemm_bf16_k(
    const __hip_bfloat16* __restrict__ A,
    const __hip_bfloat16* __restrict__ B,
    float* __restrict__ C,
    int lda, int ldb, int ldc, int K,
    const float* __restrict__ bias1,
    const float* __restrict__ bias2) {
  __shared__ __hip_bfloat16 sA[128][64];
  __shared__ __hip_bfloat16 sB[128][64];
  const int m0 = blockIdx.y << 7, n0 = blockIdx.x << 7;
  const int tid = threadIdx.x;
  const int l = tid & 63, w = tid >> 6;
  const int wm = (w & 1) << 6, wn = (w >> 1) << 6;
  const int lr = l & 15;                 // A-row / B-col / C-col within 16
  const int lk = (l >> 4) << 3;          // k-offset within 32 (8 contiguous)
  const int srow = tid >> 3;             // staging row 0..31
  const int scol = (tid & 7) << 3;       // staging col (elems), 8 bf16 = 16B

  f32x4 acc[4][4];
  #pragma unroll
  for (int i = 0; i < 4; ++i) {
    #pragma unroll
    for (int j = 0; j < 4; ++j) acc[i][j] = {0.f, 0.f, 0.f, 0.f};
  }

  for (int k0 = 0; k0 < K; k0 += 64) {
    int4 av[4], bv[4];
    #pragma unroll
    for (int r = 0; r < 4; ++r) {
      av[r] = *(const int4*)(A + (size_t)(m0 + (r << 5) + srow) * lda + k0 + scol);
      bv[r] = *(const int4*)(B + (size_t)(n0 + (r << 5) + srow) * ldb + k0 + scol);
    }
    __syncthreads();
    #pragma unroll
    for (int r = 0; r < 4; ++r) {
      *(int4*)(&sA[(r << 5) + srow][scol]) = av[r];
      *(int4*)(&sB[(r << 5) + srow][scol]) = bv[r];
    }
    __syncthreads();
    #pragma unroll
    for (int kk = 0; kk < 64; kk += 32) {
      short8 aF[4], bF[4];
      #pragma unroll
      for (int ms = 0; ms < 4; ++ms) aF[ms] = *(const short8*)(&sA[wm + (ms << 4) + lr][kk + lk]);
      #pragma unroll
      for (int ns = 0; ns < 4; ++ns) bF[ns] = *(const short8*)(&sB[wn + (ns << 4) + lr][kk + lk]);
      #pragma unroll
      for (int ms = 0; ms < 4; ++ms) {
        #pragma unroll
        for (int ns = 0; ns < 4; ++ns) {
          acc[ms][ns] = __builtin_amdgcn_mfma_f32_16x16x32_bf16(aF[ms], bF[ns], acc[ms][ns], 0, 0, 0);
        }
      }
    }
  }

  // epilogue: C/D frag layout col = lane&15, row = (lane>>4)*4 + reg
  const int rbase = (l >> 4) << 2;
  #pragma unroll
  for (int ms = 0; ms < 4; ++ms) {
    #pragma unroll
    for (int ns = 0; ns < 4; ++ns) {
      const int col = n0 + wn + (ns << 4) + lr;
      float badd = bias1 ? bias1[col] : 0.f;
      #pragma unroll
      for (int r = 0; r < 4; ++r) {
        const int row = m0 + wm + (ms << 4) + rbase + r;
        float v = acc[ms][ns][r] + badd;
        if (bias2) v += bias2[(size_t)(row >> 6) * G3 + col];
        C[(size_t)row * ldc + col] = v;
      }
    }
  }
}

// ---------------- one GRU timestep (f32 recurrence) ----------------
// grid (8 islices of 64, 32 batches), 256 threads.
// hp = h @ Whh^T via whhT[k][gaterow] streamed (coalesced), split-K over 4 chunks.
__global__ __launch_bounds__(256) void gru_step_k(
    const float* __restrict__ xp,       // [2048,1536], row m=b*64+t, includes bih
    const float* __restrict__ whhT,     // [512][1536]
    const float* __restrict__ bhh,      // [1536]
    const float* __restrict__ h_in,     // [32,512]
    float* __restrict__ h_out,          // [32,512]
    __hip_bfloat16* __restrict__ dec_out, // null or [2048,512]
    int t) {
  const int b = blockIdx.y;
  const int i0 = blockIdx.x << 6;
  __shared__ float sH[Hh];
  __shared__ float sRed[4][64][3];
  const int tid = threadIdx.x;
  for (int j = tid; j < Hh; j += 256) sH[j] = h_in[b * Hh + j];
  __syncthreads();

  const int i = tid & 63, kc = tid >> 6;
  float ar = 0.f, az = 0.f, an = 0.f;
  const float* wp = whhT + (size_t)(kc * 128) * G3 + i0 + i;
  const float* hp = sH + kc * 128;
  #pragma unroll 4
  for (int k = 0; k < 128; ++k) {
    float hv = hp[k];
    ar = fmaf(wp[0],    hv, ar);
    az = fmaf(wp[512],  hv, az);
    an = fmaf(wp[1024], hv, an);
    wp += G3;
  }
  sRed[kc][i][0] = ar;
  sRed[kc][i][1] = az;
  sRed[kc][i][2] = an;
  __syncthreads();

  if (tid < 64) {
    float hr = sRed[0][tid][0] + sRed[1][tid][0] + sRed[2][tid][0] + sRed[3][tid][0];
    float hz = sRed[0][tid][1] + sRed[1][tid][1] + sRed[2][tid][1] + sRed[3][tid][1];
    float hn = sRed[0][tid][2] + sRed[1][tid][2] + sRed[2][tid][2] + sRed[3][tid][2];
    const int gi = i0 + tid;
    const int m = b * Tt + t;
    hr += bhh[gi];
    hz += bhh[512 + gi];
    hn += bhh[1024 + gi];
    const float xr = xp[(size_t)m * G3 + gi];
    const float xz = xp[(size_t)m * G3 + 512 + gi];
    const float xn = xp[(size_t)m * G3 + 1024 + gi];
    const float r = 1.f / (1.f + __expf(-(xr + hr)));
    const float z = 1.f / (1.f + __expf(-(xz + hz)));
    const float n = tanhf(xn + r * hn);
    const float hv = (1.f - z) * n + z * sH[gi];
    h_out[b * Hh + gi] = hv;
    if (dec_out) dec_out[(size_t)m * Hh + gi] = __float2bfloat16(hv);
  }
}

// ---------------- in-place row log-softmax over V=32000 (one WG per row) ----------------
__global__ __launch_bounds__(256) void row_logsoftmax_k(float* __restrict__ X) {
  const int row = blockIdx.x;
  float4* p4 = (float4*)(X + (size_t)row * Vv);
  const int n4 = Vv / 4;  // 8000
  const int tid = threadIdx.x;
  float m = -3.4e38f, s = 0.f;
  for (int j = tid; j < n4; j += 256) {
    float4 v = p4[j];
    float xs[4] = {v.x, v.y, v.z, v.w};
    #pragma unroll
    for (int q = 0; q < 4; ++q) {
      float x = xs[q];
      if (x > m) { s = s * __expf(m - x) + 1.f; m = x; }
      else       { s += __expf(x - m); }
    }
  }
  #pragma unroll
  for (int off = 32; off > 0; off >>= 1) {
    float mo = __shfl_down(m, off);
    float so = __shfl_down(s, off);
    float M = fmaxf(m, mo);
    s = s * __expf(m - M) + so * __expf(mo - M);
    m = M;
  }
  __shared__ float sm[4], ss[4];
  if ((tid & 63) == 0) { sm[tid >> 6] = m; ss[tid >> 6] = s; }
  __syncthreads();
  const float M4 = fmaxf(fmaxf(sm[0], sm[1]), fmaxf(sm[2], sm[3]));
  const float S = ss[0] * __expf(sm[0] - M4) + ss[1] * __expf(sm[1] - M4) +
                  ss[2] * __expf(sm[2] - M4) + ss[3] * __expf(sm[3] - M4);
  const float c = M4 + __logf(S);
  for (int j = tid; j < n4; j += 256) {
    float4 v = p4[j];
    v.x -= c; v.y -= c; v.z -= c; v.w -= c;
    p4[j] = v;
  }
}

}  // namespace

extern "C" void kernel_launch(void* const* d_in, const int* in_sizes, int n_in,
                              void* d_out, int out_size, void* d_ws, size_t ws_size,
                              hipStream_t stream) {
  (void)in_sizes; (void)n_in; (void)out_size; (void)ws_size;
  const int*   in_seq  = (const int*)d_in[0];
  const int*   tgt_seq = (const int*)d_in[1];
  const float* enc_emb = (const float*)d_in[2];
  const float* enc_Wih = (const float*)d_in[3];
  const float* enc_Whh = (const float*)d_in[4];
  const float* enc_bih = (const float*)d_in[5];
  const float* enc_bhh = (const float*)d_in[6];
  const float* dec_emb = (const float*)d_in[7];
  const float* dec_Wih = (const float*)d_in[8];
  const float* dec_Whh = (const float*)d_in[9];
  const float* dec_bih = (const float*)d_in[10];
  const float* dec_bhh = (const float*)d_in[11];
  const float* out_W   = (const float*)d_in[12];
  const float* out_b   = (const float*)d_in[13];
  float* out = (float*)d_out;

  char* ws = (char*)d_ws;
  size_t off = 0;
  auto alloc = [&](size_t bytes) -> void* {
    void* p = (void*)(ws + off);
    off += (bytes + 255) & ~(size_t)255;
    return p;
  };
  float* whhT_e            = (float*)alloc((size_t)512 * 1536 * 4);
  float* whhT_d            = (float*)alloc((size_t)512 * 1536 * 4);
  __hip_bfloat16* encWih_bf = (__hip_bfloat16*)alloc((size_t)1536 * 512 * 2);
  __hip_bfloat16* decWih_bf = (__hip_bfloat16*)alloc((size_t)1536 * 1024 * 2);
  __hip_bfloat16* outW_bf   = (__hip_bfloat16*)alloc((size_t)32000 * 512 * 2);
  __hip_bfloat16* encX_bf   = (__hip_bfloat16*)alloc((size_t)2048 * 512 * 2);
  __hip_bfloat16* decX_bf   = (__hip_bfloat16*)alloc((size_t)2048 * 512 * 2);
  float* enc_xp            = (float*)alloc((size_t)2048 * 1536 * 4);
  float* dec_xp            = (float*)alloc((size_t)2048 * 1536 * 4);
  float* tp                = (float*)alloc((size_t)128 * 1536 * 4);
  __hip_bfloat16* th_bf     = (__hip_bfloat16*)alloc((size_t)128 * 512 * 2);
  float* ha                = (float*)alloc((size_t)32 * 512 * 4);
  float* hb                = (float*)alloc((size_t)32 * 512 * 4);
  __hip_bfloat16* decOut_bf = (__hip_bfloat16*)alloc((size_t)2048 * 512 * 2);

  // --- weight preprocessing ---
  cvt_bf16_k<<<768, 256, 0, stream>>>(enc_Wih, encWih_bf, 1536 * 512 / 4);
  cvt_bf16_k<<<1536, 256, 0, stream>>>(dec_Wih, decWih_bf, 1536 * 1024 / 4);
  cvt_bf16_k<<<16000, 256, 0, stream>>>(out_W, outW_bf, 32000 * 512 / 4);
  transpose_k<<<dim3(16, 48), dim3(32, 8), 0, stream>>>(enc_Whh, 512, 0, whhT_e);
  transpose_k<<<dim3(16, 48), dim3(32, 8), 0, stream>>>(dec_Whh, 512, 0, whhT_d);

  // --- embeddings ---
  embed_k<<<2048, 128, 0, stream>>>(in_seq, enc_emb, encX_bf, 0);
  embed_k<<<2048, 128, 0, stream>>>(tgt_seq, dec_emb, decX_bf, 1);

  // --- encoder xp = enc_x @ Wih^T + bih : [2048,1536] ---
  gemm_bf16_k<<<dim3(12, 16), 256, 0, stream>>>(encX_bf, encWih_bf, enc_xp,
                                                512, 512, G3, 512, enc_bih, nullptr);

  // --- encoder GRU, 64 steps ---
  zero_k<<<64, 256, 0, stream>>>(ha, Bb * Hh);
  for (int t = 0; t < Tt; ++t) {
    const float* hin = (t & 1) ? hb : ha;
    float* hout = (t & 1) ? ha : hb;
    gru_step_k<<<dim3(8, 32), 256, 0, stream>>>(enc_xp, whhT_e, enc_bhh, hin, hout, nullptr, t);
  }
  // t=63 wrote ha -> thought lives in ha

  // --- tp = relu(thought) @ dec_Wih[:,512:]^T + dec_bih : [128(pad),1536] ---
  thought_prep_k<<<128, 128, 0, stream>>>(ha, th_bf);
  gemm_bf16_k<<<dim3(12, 1), 256, 0, stream>>>(th_bf, decWih_bf + 512, tp,
                                               512, 1024, G3, 512, dec_bih, nullptr);

  // --- decoder xp = relu(dec_x) @ dec_Wih[:,:512]^T + tp[b] : [2048,1536] ---
  gemm_bf16_k<<<dim3(12, 16), 256, 0, stream>>>(decX_bf, decWih_bf, dec_xp,
                                                512, 1024, G3, 512, nullptr, tp);

  // --- decoder GRU, 64 steps ---
  zero_k<<<64, 256, 0, stream>>>(ha, Bb * Hh);
  for (int t = 0; t < Tt; ++t) {
    const float* hin = (t & 1) ? hb : ha;
    float* hout = (t & 1) ? ha : hb;
    gru_step_k<<<dim3(8, 32), 256, 0, stream>>>(dec_xp, whhT_d, dec_bhh, hin, hout, decOut_bf, t);
  }

  // --- logits = dec_out @ out_W^T + out_b -> d_out (f32, in place) ---
  gemm_bf16_k<<<dim3(250, 16), 256, 0, stream>>>(decOut_bf, outW_bf, out,
                                                 512, 512, Vv, 512, out_b, nullptr);

  // --- in-place log-softmax over V ---
  row_logsoftmax_k<<<2048, 256, 0, stream>>>(out);
}

// Round 2
// 1271.688 us; speedup vs baseline: 1.4081x; 1.4081x over previous
//
#include <hip/hip_runtime.h>
#include <hip/hip_bf16.h>
#include <cstdint>
#include <cstddef>

namespace {

constexpr int Hh = 512;
constexpr int G3 = 1536;   // 3*H
constexpr int Bb = 32;
constexpr int Tt = 64;
constexpr int Vv = 32000;

typedef __attribute__((ext_vector_type(8))) short short8;
typedef __attribute__((ext_vector_type(4))) float f32x4;

// ---------------- f32 -> bf16 convert (vectorized) ----------------
__global__ void cvt_bf16_k(const float* __restrict__ src, __hip_bfloat16* __restrict__ dst, int n4) {
  int i = blockIdx.x * blockDim.x + threadIdx.x;
  if (i >= n4) return;
  float4 v = ((const float4*)src)[i];
  union { __hip_bfloat16 h[4]; uint2 u; } o;
  o.h[0] = __float2bfloat16(v.x);
  o.h[1] = __float2bfloat16(v.y);
  o.h[2] = __float2bfloat16(v.z);
  o.h[3] = __float2bfloat16(v.w);
  ((uint2*)dst)[i] = o.u;
}

// ---------------- pack Whh[1536][512] -> P[k][i][{r,z,n,0}] float4, 4MB ----------------
__global__ void pack_whh_k(const float* __restrict__ Whh, float* __restrict__ P) {
  __shared__ float tw[3][32][65];
  const int k0 = blockIdx.x * 64, i0 = blockIdx.y * 32;
  const int t = threadIdx.x;               // 256
  const int kk = t & 63, r4 = t >> 6;      // r4 0..3
  for (int ri = r4; ri < 96; ri += 4) {
    const int g = ri >> 5, ii = ri & 31;
    tw[g][ii][kk] = Whh[(size_t)(g * 512 + i0 + ii) * 512 + k0 + kk];
  }
  __syncthreads();
  const int ii = t & 31, kq = t >> 5;      // kq 0..7
  for (int kk2 = kq; kk2 < 64; kk2 += 8) {
    float4 v = {tw[0][ii][kk2], tw[1][ii][kk2], tw[2][ii][kk2], 0.f};
    ((float4*)P)[(size_t)(k0 + kk2) * 512 + i0 + ii] = v;
  }
}

// ---------------- embedding gather (optionally relu) -> bf16 [2048][512] ----------------
__global__ void embed_k(const int* __restrict__ idx, const float* __restrict__ emb,
                        __hip_bfloat16* __restrict__ outp, int do_relu) {
  int row = blockIdx.x;            // 0..2047 (= b*64+t)
  int r = idx[row];
  float4 v = ((const float4*)(emb + (size_t)r * Hh))[threadIdx.x];  // 128 thr * 4
  if (do_relu) {
    v.x = fmaxf(v.x, 0.f); v.y = fmaxf(v.y, 0.f);
    v.z = fmaxf(v.z, 0.f); v.w = fmaxf(v.w, 0.f);
  }
  union { __hip_bfloat16 h[4]; uint2 u; } o;
  o.h[0] = __float2bfloat16(v.x);
  o.h[1] = __float2bfloat16(v.y);
  o.h[2] = __float2bfloat16(v.z);
  o.h[3] = __float2bfloat16(v.w);
  ((uint2*)(outp + (size_t)row * Hh))[threadIdx.x] = o.u;
}

// ---------------- zero f32 ----------------
__global__ void zero_k(float* __restrict__ p, int n) {
  int i = blockIdx.x * blockDim.x + threadIdx.x;
  if (i < n) p[i] = 0.f;
}

// ---------------- relu(thought)->bf16, padded to 128 rows ----------------
__global__ void thought_prep_k(const float* __restrict__ th, __hip_bfloat16* __restrict__ outp) {
  int row = blockIdx.x;  // 0..127
  float4 v = {0.f, 0.f, 0.f, 0.f};
  if (row < Bb) v = ((const float4*)(th + (size_t)row * Hh))[threadIdx.x];
  v.x = fmaxf(v.x, 0.f); v.y = fmaxf(v.y, 0.f);
  v.z = fmaxf(v.z, 0.f); v.w = fmaxf(v.w, 0.f);
  union { __hip_bfloat16 h[4]; uint2 u; } o;
  o.h[0] = __float2bfloat16(v.x);
  o.h[1] = __float2bfloat16(v.y);
  o.h[2] = __float2bfloat16(v.z);
  o.h[3] = __float2bfloat16(v.w);
  ((uint2*)(outp + (size_t)row * Hh))[threadIdx.x] = o.u;
}

// ---------------- bf16 MFMA GEMM: C[M,N](f32) = A[M,K] * B[N,K]^T (+bias1[n]) (+bias2[(m>>6)*1536+n]) ----------------
// tile 128x128, BK=64, 256 threads (4 waves, each 64x64), single-buffered LDS, reg-staged.
// Epilogue stages each wave's 16x64 f32 sub-tile through LDS for fully-coalesced
// float4 stores (256B contiguous per row) -- avoids partial-cacheline write-amp.
__global__ __launch_bounds__(256) void gemm_bf16_k(
    const __hip_bfloat16* __restrict__ A,
    const __hip_bfloat16* __restrict__ B,
    float* __restrict__ C,
    int lda, int ldb, int ldc, int K,
    const float* __restrict__ bias1,
    const float* __restrict__ bias2) {
  __shared__ __align__(16) char smem[32768];
  auto sA = (__hip_bfloat16(*)[64])smem;            // [128][64]
  auto sB = (__hip_bfloat16(*)[64])(smem + 16384);  // [128][64]
  const int m0 = blockIdx.y << 7, n0 = blockIdx.x << 7;
  const int tid = threadIdx.x;
  const int l = tid & 63, w = tid >> 6;
  const int wm = (w & 1) << 6, wn = (w >> 1) << 6;
  const int lr = l & 15;                 // A-row / B-col / C-col within 16
  const int lk = (l >> 4) << 3;          // k-offset within 32 (8 contiguous)
  const int srow = tid >> 3;             // staging row 0..31
  const int scol = (tid & 7) << 3;       // staging col (elems), 8 bf16 = 16B

  f32x4 acc[4][4];
  #pragma unroll
  for (int i = 0; i < 4; ++i) {
    #pragma unroll
    for (int j = 0; j < 4; ++j) acc[i][j] = {0.f, 0.f, 0.f, 0.f};
  }

  for (int k0 = 0; k0 < K; k0 += 64) {
    int4 av[4], bv[4];
    #pragma unroll
    for (int r = 0; r < 4; ++r) {
      av[r] = *(const int4*)(A + (size_t)(m0 + (r << 5) + srow) * lda + k0 + scol);
      bv[r] = *(const int4*)(B + (size_t)(n0 + (r << 5) + srow) * ldb + k0 + scol);
    }
    __syncthreads();
    #pragma unroll
    for (int r = 0; r < 4; ++r) {
      *(int4*)(&sA[(r << 5) + srow][scol]) = av[r];
      *(int4*)(&sB[(r << 5) + srow][scol]) = bv[r];
    }
    __syncthreads();
    #pragma unroll
    for (int kk = 0; kk < 64; kk += 32) {
      short8 aF[4], bF[4];
      #pragma unroll
      for (int ms = 0; ms < 4; ++ms) aF[ms] = *(const short8*)(&sA[wm + (ms << 4) + lr][kk + lk]);
      #pragma unroll
      for (int ns = 0; ns < 4; ++ns) bF[ns] = *(const short8*)(&sB[wn + (ns << 4) + lr][kk + lk]);
      #pragma unroll
      for (int ms = 0; ms < 4; ++ms) {
        #pragma unroll
        for (int ns = 0; ns < 4; ++ns) {
          acc[ms][ns] = __builtin_amdgcn_mfma_f32_16x16x32_bf16(aF[ms], bF[ns], acc[ms][ns], 0, 0, 0);
        }
      }
    }
  }

  // ---- epilogue: LDS round-trip per 16-row group, coalesced float4 stores ----
  __syncthreads();                          // all waves done with sA/sB tiles
  float* sg = (float*)smem + w * 1088;      // per-wave 16 rows * 68 f32 (stride-68: 2-way max bank alias)
  const int r2w = l >> 4;                   // 0..3
  const int cw = l & 15;
  const int rbase = r2w << 2;
  #pragma unroll
  for (int ms = 0; ms < 4; ++ms) {
    #pragma unroll
    for (int ns = 0; ns < 4; ++ns) {
      #pragma unroll
      for (int r = 0; r < 4; ++r) sg[(rbase + r) * 68 + (ns << 4) + lr] = acc[ms][ns][r];
    }
    // same-wave LDS ops are in-order; no barrier needed
    #pragma unroll
    for (int q = 0; q < 4; ++q) {
      const int srow2 = (q << 2) + r2w;
      float4 v = *(const float4*)&sg[srow2 * 68 + (cw << 2)];
      const int row = m0 + wm + (ms << 4) + srow2;
      const int col = n0 + wn + (cw << 2);
      if (bias1) {
        float4 b1 = *(const float4*)&bias1[col];
        v.x += b1.x; v.y += b1.y; v.z += b1.z; v.w += b1.w;
      }
      if (bias2) {
        float4 b2 = *(const float4*)&bias2[(size_t)(row >> 6) * G3 + col];
        v.x += b2.x; v.y += b2.y; v.z += b2.z; v.w += b2.w;
      }
      *(float4*)&C[(size_t)row * ldc + col] = v;
    }
  }
}

// ---------------- one GRU timestep (f32 recurrence), batched ----------------
// grid (16 i-slices of 32, 8 b-groups of 4), 512 threads.
// whhP layout: [k][i][{r,z,n,0}] float4 -> one 16B coalesced load feeds 12 FMAs.
__global__ __launch_bounds__(512) void gru_step2_k(
    const float* __restrict__ xp,       // [2048,1536], row m=b*64+t, includes bih(+tp)
    const float* __restrict__ whhP,     // [512k][512i][4] f32
    const float* __restrict__ bhh,      // [1536]
    const float* __restrict__ h_in,     // [32,512]
    float* __restrict__ h_out,          // [32,512]
    __hip_bfloat16* __restrict__ dec_out, // null or [2048,512]
    int tstep) {
  __shared__ float sH[4 * 512];
  __shared__ float sRed[16 * 32 * 13];
  const int t = threadIdx.x;
  const int i0 = blockIdx.x << 5;
  const int bg = blockIdx.y;
  ((float4*)sH)[t] = ((const float4*)(h_in + (size_t)bg * 4 * 512))[t];
  __syncthreads();

  const int il = t & 31, kc = t >> 5;   // kc 0..15 (32 k each)
  float acc[12];
  #pragma unroll
  for (int v = 0; v < 12; ++v) acc[v] = 0.f;
  union F4 { float4 v; float f[4]; };
  const float4* wb = (const float4*)whhP + i0 + il;
  const int kb0 = kc << 5;
  #pragma unroll 2
  for (int kk4 = 0; kk4 < 8; ++kk4) {
    const int kb = kb0 + (kk4 << 2);
    F4 hb[4];
    #pragma unroll
    for (int b = 0; b < 4; ++b) hb[b].v = *(const float4*)&sH[b * 512 + kb];
    #pragma unroll
    for (int j = 0; j < 4; ++j) {
      float4 wv = wb[(size_t)(kb + j) << 9];
      #pragma unroll
      for (int b = 0; b < 4; ++b) {
        const float hv = hb[b].f[j];
        acc[b * 3 + 0] = fmaf(wv.x, hv, acc[b * 3 + 0]);
        acc[b * 3 + 1] = fmaf(wv.y, hv, acc[b * 3 + 1]);
        acc[b * 3 + 2] = fmaf(wv.z, hv, acc[b * 3 + 2]);
      }
    }
  }
  {
    float* red = &sRed[(kc * 32 + il) * 13];
    #pragma unroll
    for (int v = 0; v < 12; ++v) red[v] = acc[v];
  }
  __syncthreads();

  if (t < 128) {
    const int b = t >> 5, i2 = t & 31;
    float s0 = 0.f, s1 = 0.f, s2 = 0.f;
    #pragma unroll
    for (int kc2 = 0; kc2 < 16; ++kc2) {
      const float* rp = &sRed[(kc2 * 32 + i2) * 13 + b * 3];
      s0 += rp[0]; s1 += rp[1]; s2 += rp[2];
    }
    const int gi = i0 + i2;
    const int bb = bg * 4 + b;
    const int m = bb * Tt + tstep;
    const float hr = s0 + bhh[gi];
    const float hz = s1 + bhh[512 + gi];
    const float hn = s2 + bhh[1024 + gi];
    const float xr = xp[(size_t)m * G3 + gi];
    const float xz = xp[(size_t)m * G3 + 512 + gi];
    const float xn = xp[(size_t)m * G3 + 1024 + gi];
    const float r = 1.f / (1.f + __expf(-(xr + hr)));
    const float z = 1.f / (1.f + __expf(-(xz + hz)));
    const float n = tanhf(xn + r * hn);
    const float hnew = (1.f - z) * n + z * sH[b * 512 + gi];
    h_out[(size_t)bb * 512 + gi] = hnew;
    if (dec_out) dec_out[(size_t)m * 512 + gi] = __float2bfloat16(hnew);
  }
}

// ---------------- in-place row log-softmax over V=32000 (one WG per row) ----------------
__global__ __launch_bounds__(256) void row_logsoftmax_k(float* __restrict__ X) {
  const int row = blockIdx.x;
  float4* p4 = (float4*)(X + (size_t)row * Vv);
  const int n4 = Vv / 4;  // 8000
  const int tid = threadIdx.x;
  float m = -3.4e38f, s = 0.f;
  for (int j = tid; j < n4; j += 256) {
    float4 v = p4[j];
    float xs[4] = {v.x, v.y, v.z, v.w};
    #pragma unroll
    for (int q = 0; q < 4; ++q) {
      float x = xs[q];
      if (x > m) { s = s * __expf(m - x) + 1.f; m = x; }
      else       { s += __expf(x - m); }
    }
  }
  #pragma unroll
  for (int off = 32; off > 0; off >>= 1) {
    float mo = __shfl_down(m, off);
    float so = __shfl_down(s, off);
    float M = fmaxf(m, mo);
    s = s * __expf(m - M) + so * __expf(mo - M);
    m = M;
  }
  __shared__ float sm[4], ss[4];
  if ((tid & 63) == 0) { sm[tid >> 6] = m; ss[tid >> 6] = s; }
  __syncthreads();
  const float M4 = fmaxf(fmaxf(sm[0], sm[1]), fmaxf(sm[2], sm[3]));
  const float S = ss[0] * __expf(sm[0] - M4) + ss[1] * __expf(sm[1] - M4) +
                  ss[2] * __expf(sm[2] - M4) + ss[3] * __expf(sm[3] - M4);
  const float c = M4 + __logf(S);
  for (int j = tid; j < n4; j += 256) {
    float4 v = p4[j];
    v.x -= c; v.y -= c; v.z -= c; v.w -= c;
    p4[j] = v;
  }
}

}  // namespace

extern "C" void kernel_launch(void* const* d_in, const int* in_sizes, int n_in,
                              void* d_out, int out_size, void* d_ws, size_t ws_size,
                              hipStream_t stream) {
  (void)in_sizes; (void)n_in; (void)out_size; (void)ws_size;
  const int*   in_seq  = (const int*)d_in[0];
  const int*   tgt_seq = (const int*)d_in[1];
  const float* enc_emb = (const float*)d_in[2];
  const float* enc_Wih = (const float*)d_in[3];
  const float* enc_Whh = (const float*)d_in[4];
  const float* enc_bih = (const float*)d_in[5];
  const float* enc_bhh = (const float*)d_in[6];
  const float* dec_emb = (const float*)d_in[7];
  const float* dec_Wih = (const float*)d_in[8];
  const float* dec_Whh = (const float*)d_in[9];
  const float* dec_bih = (const float*)d_in[10];
  const float* dec_bhh = (const float*)d_in[11];
  const float* out_W   = (const float*)d_in[12];
  const float* out_b   = (const float*)d_in[13];
  float* out = (float*)d_out;

  char* ws = (char*)d_ws;
  size_t off = 0;
  auto alloc = [&](size_t bytes) -> void* {
    void* p = (void*)(ws + off);
    off += (bytes + 255) & ~(size_t)255;
    return p;
  };
  float* whhP_e            = (float*)alloc((size_t)512 * 512 * 16);   // 4MB packed
  float* whhP_d            = (float*)alloc((size_t)512 * 512 * 16);
  __hip_bfloat16* encWih_bf = (__hip_bfloat16*)alloc((size_t)1536 * 512 * 2);
  __hip_bfloat16* decWih_bf = (__hip_bfloat16*)alloc((size_t)1536 * 1024 * 2);
  __hip_bfloat16* outW_bf   = (__hip_bfloat16*)alloc((size_t)32000 * 512 * 2);
  __hip_bfloat16* encX_bf   = (__hip_bfloat16*)alloc((size_t)2048 * 512 * 2);
  __hip_bfloat16* decX_bf   = (__hip_bfloat16*)alloc((size_t)2048 * 512 * 2);
  float* enc_xp            = (float*)alloc((size_t)2048 * 1536 * 4);
  float* dec_xp            = (float*)alloc((size_t)2048 * 1536 * 4);
  float* tp                = (float*)alloc((size_t)128 * 1536 * 4);
  __hip_bfloat16* th_bf     = (__hip_bfloat16*)alloc((size_t)128 * 512 * 2);
  float* ha                = (float*)alloc((size_t)32 * 512 * 4);
  float* hb                = (float*)alloc((size_t)32 * 512 * 4);
  __hip_bfloat16* decOut_bf = (__hip_bfloat16*)alloc((size_t)2048 * 512 * 2);

  // --- weight preprocessing ---
  cvt_bf16_k<<<768, 256, 0, stream>>>(enc_Wih, encWih_bf, 1536 * 512 / 4);
  cvt_bf16_k<<<1536, 256, 0, stream>>>(dec_Wih, decWih_bf, 1536 * 1024 / 4);
  cvt_bf16_k<<<16000, 256, 0, stream>>>(out_W, outW_bf, 32000 * 512 / 4);
  pack_whh_k<<<dim3(8, 16), 256, 0, stream>>>(enc_Whh, whhP_e);
  pack_whh_k<<<dim3(8, 16), 256, 0, stream>>>(dec_Whh, whhP_d);

  // --- embeddings ---
  embed_k<<<2048, 128, 0, stream>>>(in_seq, enc_emb, encX_bf, 0);
  embed_k<<<2048, 128, 0, stream>>>(tgt_seq, dec_emb, decX_bf, 1);

  // --- encoder xp = enc_x @ Wih^T + bih : [2048,1536] ---
  gemm_bf16_k<<<dim3(12, 16), 256, 0, stream>>>(encX_bf, encWih_bf, enc_xp,
                                                512, 512, G3, 512, enc_bih, nullptr);

  // --- encoder GRU, 64 steps ---
  zero_k<<<64, 256, 0, stream>>>(ha, Bb * Hh);
  for (int t = 0; t < Tt; ++t) {
    const float* hin = (t & 1) ? hb : ha;
    float* hout = (t & 1) ? ha : hb;
    gru_step2_k<<<dim3(16, 8), 512, 0, stream>>>(enc_xp, whhP_e, enc_bhh, hin, hout, nullptr, t);
  }
  // t=63 wrote ha -> thought lives in ha

  // --- tp = relu(thought) @ dec_Wih[:,512:]^T + dec_bih : [128(pad),1536] ---
  thought_prep_k<<<128, 128, 0, stream>>>(ha, th_bf);
  gemm_bf16_k<<<dim3(12, 1), 256, 0, stream>>>(th_bf, decWih_bf + 512, tp,
                                               512, 1024, G3, 512, dec_bih, nullptr);

  // --- decoder xp = relu(dec_x) @ dec_Wih[:,:512]^T + tp[b] : [2048,1536] ---
  gemm_bf16_k<<<dim3(12, 16), 256, 0, stream>>>(decX_bf, decWih_bf, dec_xp,
                                                512, 1024, G3, 512, nullptr, tp);

  // --- decoder GRU, 64 steps ---
  zero_k<<<64, 256, 0, stream>>>(ha, Bb * Hh);
  for (int t = 0; t < Tt; ++t) {
    const float* hin = (t & 1) ? hb : ha;
    float* hout = (t & 1) ? ha : hb;
    gru_step2_k<<<dim3(16, 8), 512, 0, stream>>>(dec_xp, whhP_d, dec_bhh, hin, hout, decOut_bf, t);
  }

  // --- logits = dec_out @ out_W^T + out_b -> d_out (f32, in place) ---
  gemm_bf16_k<<<dim3(250, 16), 256, 0, stream>>>(decOut_bf, outW_bf, out,
                                                 512, 512, Vv, 512, out_b, nullptr);

  // --- in-place log-softmax over V ---
  row_logsoftmax_k<<<2048, 256, 0, stream>>>(out);
}